// Round 10
// baseline (122.814 us; speedup 1.0000x reference)
//
#include <hip/hip_runtime.h>

#define IN_CH    16
#define OUT_CH   64
#define SET_LEN  64
#define BB       8
#define HH       56
#define WW       56

#define TILEROWS 8              // output rows per block (56 = 7*8)
#define NTILES   7
#define LDSROWS  (TILEROWS + 2) // staged rows incl. halo
#define LROW     56             // exactly the data columns; 224B row stride
#define LDS_XN   (IN_CH * LDSROWS * LROW)   // 8960 floats = 35840 B
#define NVEC     (IN_CH * LDSROWS * 14)     // 2240 float4 transfers

#define WS_NEEDED (OUT_CH * SET_LEN * 12 * 4)   // 196608 B

typedef float f32x2 __attribute__((ext_vector_type(2)));
typedef float f32x4 __attribute__((ext_vector_type(4)));

static __device__ __forceinline__ f32x2 splat2(float s) { return (f32x2){s, s}; }

// ---------------- pre-kernel: per-oc counting sort + weight gather ----------------
// ws layout per entry (12 floats, 48B): w0..w8, bias, chan(bits), pad
__global__ __launch_bounds__(64)
void rptn_presort(const float* __restrict__ w, const float* __restrict__ bias,
                  const int* __restrict__ idx, float* __restrict__ ws_w) {
    const int oc = blockIdx.x;
    const int t  = threadIdx.x;
    __shared__ int cnt[IN_CH], pos[IN_CH], eord[SET_LEN];

    if (t < IN_CH) cnt[t] = 0;
    __syncthreads();
    const int e = idx[oc * SET_LEN + t];
    const int c = e >> 8;
    atomicAdd(&cnt[c], 1);
    __syncthreads();
    if (t == 0) {
        int run = 0;
        for (int i = 0; i < IN_CH; ++i) { pos[i] = run; run += cnt[i]; }
    }
    __syncthreads();
    const int p = atomicAdd(&pos[c], 1);
    eord[p] = e;
    __syncthreads();

    const int    es  = eord[t];
    float*       dst = ws_w + ((size_t)oc * SET_LEN + t) * 12;
    const float* src = w + es * 9;
    #pragma unroll
    for (int i = 0; i < 9; ++i) dst[i] = src[i];
    dst[9]  = bias[es];
    dst[10] = __int_as_float(es >> 8);
    dst[11] = 0.0f;
}

// ---------------- main fused kernel (weights via scalar loads) ----------------
__global__ __launch_bounds__(256, 2)
void rptn_fused_kernel(const float* __restrict__ x,
                       const float* __restrict__ ws_w,
                       float*       __restrict__ out) {
    const int oc   = blockIdx.x;   // fastest-varying -> x tile reused across oc in L2
    const int tile = blockIdx.y;
    const int b    = blockIdx.z;
    const int tid  = threadIdx.x;
    const int tx   = tid & 63;
    const int grp  = __builtin_amdgcn_readfirstlane(tid >> 6); // wave-uniform

    __shared__ float s_x[LDS_XN];

    // ---- stage x tile: aligned vec4 loads + vec4 LDS writes, fully pipelined ----
    const int r0 = tile * TILEROWS;
    const float* xb = x + (size_t)b * IN_CH * HH * WW;
    #pragma unroll
    for (int it = 0; it < 9; ++it) {
        const int v = tid + it * 256;
        if (it < 8 || v < NVEC) {                  // last round: tid<192
            const int c   = v / (LDSROWS * 14);
            const int rem = v - c * (LDSROWS * 14);
            const int r   = rem / 14;
            const int q   = rem - r * 14;
            const int gr  = r0 - 1 + r;
            f32x4 val = {0, 0, 0, 0};
            if ((unsigned)gr < (unsigned)HH)
                val = *(const f32x4*)(xb + (c * HH + gr) * WW + q * 4);
            *(f32x4*)&s_x[(c * LDSROWS + r) * LROW + q * 4] = val;
        }
    }
    __syncthreads();

    // ---- fused conv + bias + running max; 2 rows per lane ----
    const bool  lanev = (tx < WW);
    const int   txr   = lanev ? tx : 0;            // clamp for safe LDS reads
    const int   txl   = (txr > 0)  ? txr - 1 : 0;  // in-row clamp; masked by lm
    const int   txp   = (txr < 55) ? txr + 1 : 55; // in-row clamp; masked by rm
    const float lm    = (txr == 0)  ? 0.0f : 1.0f; // left-edge tap mask
    const float rm    = (txr == 55) ? 0.0f : 1.0f; // right-edge tap mask

    f32x2 acc = { -__builtin_inff(), -__builtin_inff() };
    int ccur = -1;
    f32x2 v00={0,0},v01={0,0},v02={0,0};
    f32x2 v10={0,0},v11={0,0},v12={0,0};
    f32x2 v20={0,0},v21={0,0},v22={0,0};

    // uniform base: depends only on blockIdx -> scalar loads, affine in k
    const f32x4* wt = (const f32x4*)ws_w + (size_t)oc * SET_LEN * 3;

    #pragma unroll 4
    for (int k = 0; k < SET_LEN; ++k) {
        const f32x4 q0 = wt[k * 3 + 0];     // w0 w1 w2 w3     (s_load_dwordx4)
        const f32x4 q1 = wt[k * 3 + 1];     // w4 w5 w6 w7
        const f32x4 q2 = wt[k * 3 + 2];     // w8 bias chan pad
        const int c = __float_as_int(q2.z);
        if (c != ccur) {                    // wave-uniform branch (~16 of 64 iters)
            ccur = c;
            const float* sp = &s_x[(c * LDSROWS + grp * 2) * LROW];
            const float n00=sp[txl]*lm,        n01=sp[txr],        n02=sp[txp]*rm;
            const float n10=sp[LROW+txl]*lm,   n11=sp[LROW+txr],   n12=sp[LROW+txp]*rm;
            const float n20=sp[2*LROW+txl]*lm, n21=sp[2*LROW+txr], n22=sp[2*LROW+txp]*rm;
            const float n30=sp[3*LROW+txl]*lm, n31=sp[3*LROW+txr], n32=sp[3*LROW+txp]*rm;
            v00=(f32x2){n00,n10}; v01=(f32x2){n01,n11}; v02=(f32x2){n02,n12};
            v10=(f32x2){n10,n20}; v11=(f32x2){n11,n21}; v12=(f32x2){n12,n22};
            v20=(f32x2){n20,n30}; v21=(f32x2){n21,n31}; v22=(f32x2){n22,n32};
        }
        f32x2 t0 = __builtin_elementwise_fma(splat2(q0.z), v02,
                   __builtin_elementwise_fma(splat2(q0.y), v01,
                   __builtin_elementwise_fma(splat2(q0.x), v00, splat2(q2.y))));
        f32x2 t1 = __builtin_elementwise_fma(splat2(q1.y), v12,
                   __builtin_elementwise_fma(splat2(q1.x), v11,
                                             splat2(q0.w) * v10));
        f32x2 t2 = __builtin_elementwise_fma(splat2(q2.x), v22,
                   __builtin_elementwise_fma(splat2(q1.w), v21,
                                             splat2(q1.z) * v20));
        const f32x2 s = t0 + (t1 + t2);
        acc.x = fmaxf(acc.x, s.x);
        acc.y = fmaxf(acc.y, s.y);
    }

    if (lanev) {
        const size_t o = (((size_t)b * OUT_CH + oc) * HH + (r0 + grp * 2)) * WW + tx;
        out[o]      = acc.x;   // row grp*2
        out[o + WW] = acc.y;   // row grp*2 + 1
    }
}

// ---------------- fallback (R9): in-block sort + LDS weight table ----------------
__global__ __launch_bounds__(256, 2)
void rptn_fused_fallback(const float* __restrict__ x,
                         const float* __restrict__ w,
                         const float* __restrict__ bias,
                         const int*   __restrict__ idx,
                         float*       __restrict__ out) {
    const int oc   = blockIdx.x;
    const int tile = blockIdx.y;
    const int b    = blockIdx.z;
    const int tid  = threadIdx.x;
    const int tx   = tid & 63;
    const int grp  = __builtin_amdgcn_readfirstlane(tid >> 6);

    __shared__ float s_x[LDS_XN];
    __shared__ f32x4 s_w[SET_LEN * 3];
    __shared__ int   s_cnt[IN_CH];
    __shared__ int   s_pos[IN_CH];
    __shared__ int   s_eord[SET_LEN];

    if (tid < IN_CH) s_cnt[tid] = 0;
    __syncthreads();
    int my_e = 0;
    if (tid < SET_LEN) {
        my_e = idx[oc * SET_LEN + tid];
        atomicAdd(&s_cnt[my_e >> 8], 1);
    }
    __syncthreads();
    if (tid == 0) {
        int run = 0;
        for (int c = 0; c < IN_CH; ++c) { s_pos[c] = run; run += s_cnt[c]; }
    }
    __syncthreads();
    if (tid < SET_LEN) {
        int p = atomicAdd(&s_pos[my_e >> 8], 1);
        s_eord[p] = my_e;
    }
    __syncthreads();

    float* s_wf = (float*)s_w;
    for (int i = tid; i < SET_LEN * 12; i += 256) {
        const int j    = i / 12;
        const int comp = i - j * 12;
        const int e    = s_eord[j];
        float v;
        if (comp < 9)        v = w[e * 9 + comp];
        else if (comp == 9)  v = bias[e];
        else if (comp == 10) v = __int_as_float(e >> 8);
        else                 v = 0.0f;
        s_wf[j * 12 + comp] = v;
    }

    const int r0 = tile * TILEROWS;
    const float* xb = x + (size_t)b * IN_CH * HH * WW;
    #pragma unroll
    for (int it = 0; it < 9; ++it) {
        const int v = tid + it * 256;
        if (it < 8 || v < NVEC) {
            const int c   = v / (LDSROWS * 14);
            const int rem = v - c * (LDSROWS * 14);
            const int r   = rem / 14;
            const int q   = rem - r * 14;
            const int gr  = r0 - 1 + r;
            f32x4 val = {0, 0, 0, 0};
            if ((unsigned)gr < (unsigned)HH)
                val = *(const f32x4*)(xb + (c * HH + gr) * WW + q * 4);
            *(f32x4*)&s_x[(c * LDSROWS + r) * LROW + q * 4] = val;
        }
    }
    __syncthreads();

    const bool  lanev = (tx < WW);
    const int   txr   = lanev ? tx : 0;
    const int   txl   = (txr > 0)  ? txr - 1 : 0;
    const int   txp   = (txr < 55) ? txr + 1 : 55;
    const float lm    = (txr == 0)  ? 0.0f : 1.0f;
    const float rm    = (txr == 55) ? 0.0f : 1.0f;

    f32x2 acc = { -__builtin_inff(), -__builtin_inff() };
    int ccur = -1;
    f32x2 v00={0,0},v01={0,0},v02={0,0};
    f32x2 v10={0,0},v11={0,0},v12={0,0};
    f32x2 v20={0,0},v21={0,0},v22={0,0};

    #pragma unroll 2
    for (int k = 0; k < SET_LEN; ++k) {
        const f32x4 q0 = s_w[k * 3 + 0];
        const f32x4 q1 = s_w[k * 3 + 1];
        const f32x4 q2 = s_w[k * 3 + 2];
        const int c = __float_as_int(q2.z);
        if (c != ccur) {
            ccur = c;
            const float* sp = &s_x[(c * LDSROWS + grp * 2) * LROW];
            const float n00=sp[txl]*lm,        n01=sp[txr],        n02=sp[txp]*rm;
            const float n10=sp[LROW+txl]*lm,   n11=sp[LROW+txr],   n12=sp[LROW+txp]*rm;
            const float n20=sp[2*LROW+txl]*lm, n21=sp[2*LROW+txr], n22=sp[2*LROW+txp]*rm;
            const float n30=sp[3*LROW+txl]*lm, n31=sp[3*LROW+txr], n32=sp[3*LROW+txp]*rm;
            v00=(f32x2){n00,n10}; v01=(f32x2){n01,n11}; v02=(f32x2){n02,n12};
            v10=(f32x2){n10,n20}; v11=(f32x2){n11,n21}; v12=(f32x2){n12,n22};
            v20=(f32x2){n20,n30}; v21=(f32x2){n21,n31}; v22=(f32x2){n22,n32};
        }
        f32x2 t0 = __builtin_elementwise_fma(splat2(q0.z), v02,
                   __builtin_elementwise_fma(splat2(q0.y), v01,
                   __builtin_elementwise_fma(splat2(q0.x), v00, splat2(q2.y))));
        f32x2 t1 = __builtin_elementwise_fma(splat2(q1.y), v12,
                   __builtin_elementwise_fma(splat2(q1.x), v11,
                                             splat2(q0.w) * v10));
        f32x2 t2 = __builtin_elementwise_fma(splat2(q2.x), v22,
                   __builtin_elementwise_fma(splat2(q1.w), v21,
                                             splat2(q1.z) * v20));
        const f32x2 s = t0 + (t1 + t2);
        acc.x = fmaxf(acc.x, s.x);
        acc.y = fmaxf(acc.y, s.y);
    }

    if (lanev) {
        const size_t o = (((size_t)b * OUT_CH + oc) * HH + (r0 + grp * 2)) * WW + tx;
        out[o]      = acc.x;
        out[o + WW] = acc.y;
    }
}

extern "C" void kernel_launch(void* const* d_in, const int* in_sizes, int n_in,
                              void* d_out, int out_size, void* d_ws, size_t ws_size,
                              hipStream_t stream) {
    const float* x    = (const float*)d_in[0];
    const float* w    = (const float*)d_in[1];
    const float* bias = (const float*)d_in[2];
    const int*   idx  = (const int*)d_in[3];
    float*       out  = (float*)d_out;

    dim3 grid(OUT_CH, NTILES, BB);   // oc fastest -> x tile L2 reuse
    dim3 block(256);

    if (ws_size >= (size_t)WS_NEEDED) {
        float* ws_w = (float*)d_ws;
        rptn_presort<<<dim3(OUT_CH), dim3(64), 0, stream>>>(w, bias, idx, ws_w);
        rptn_fused_kernel<<<grid, block, 0, stream>>>(x, ws_w, out);
    } else {
        rptn_fused_fallback<<<grid, block, 0, stream>>>(x, w, bias, idx, out);
    }
}

// Round 13
// 116.772 us; speedup vs baseline: 1.0517x; 1.0517x over previous
//
#include <hip/hip_runtime.h>

#define IN_CH    16
#define OUT_CH   64
#define SET_LEN  64
#define BB       8
#define HH       56
#define WW       56

#define TILEROWS 8              // output rows per block (56 = 7*8)
#define NTILES   7
#define LDSROWS  (TILEROWS + 2) // staged rows incl. halo
#define LROW     56             // exactly the data columns; 224B row stride
#define LDS_XN   (IN_CH * LDSROWS * LROW)   // 8960 floats = 35840 B
#define NVEC     (IN_CH * LDSROWS * 14)     // 2240 float4 transfers

#define WS_NEEDED (OUT_CH * SET_LEN * 12 * 4)   // 196608 B

typedef float f32x2 __attribute__((ext_vector_type(2)));
typedef float f32x4 __attribute__((ext_vector_type(4)));

static __device__ __forceinline__ f32x2 splat2(float s) { return (f32x2){s, s}; }

// ---- packed-fp32 VOP3P helpers: SGPR-pair half broadcast to both lanes ----
static __device__ __forceinline__ f32x2 pk_mul_slo(unsigned long long sp, f32x2 b) {
    f32x2 d;
    asm("v_pk_mul_f32 %0, %1, %2 op_sel:[0,0] op_sel_hi:[0,1]"
        : "=v"(d) : "s"(sp), "v"(b));
    return d;
}
static __device__ __forceinline__ f32x2 pk_mul_shi(unsigned long long sp, f32x2 b) {
    f32x2 d;
    asm("v_pk_mul_f32 %0, %1, %2 op_sel:[1,0] op_sel_hi:[1,1]"
        : "=v"(d) : "s"(sp), "v"(b));
    return d;
}
static __device__ __forceinline__ f32x2 pk_fma_slo(unsigned long long sp, f32x2 b, f32x2 c) {
    f32x2 d;
    asm("v_pk_fma_f32 %0, %1, %2, %3 op_sel:[0,0,0] op_sel_hi:[0,1,1]"
        : "=v"(d) : "s"(sp), "v"(b), "v"(c));
    return d;
}
static __device__ __forceinline__ f32x2 pk_fma_shi(unsigned long long sp, f32x2 b, f32x2 c) {
    f32x2 d;
    asm("v_pk_fma_f32 %0, %1, %2, %3 op_sel:[1,0,0] op_sel_hi:[1,1,1]"
        : "=v"(d) : "s"(sp), "v"(b), "v"(c));
    return d;
}
static __device__ __forceinline__ f32x2 pk_add_vv(f32x2 a, f32x2 b) {
    f32x2 d;
    asm("v_pk_add_f32 %0, %1, %2 op_sel:[0,0] op_sel_hi:[1,1]"
        : "=v"(d) : "v"(a), "v"(b));
    return d;
}
static __device__ __forceinline__ f32x2 pk_add_shi(unsigned long long sp, f32x2 b) {
    f32x2 d;
    asm("v_pk_add_f32 %0, %1, %2 op_sel:[1,0] op_sel_hi:[1,1]"
        : "=v"(d) : "s"(sp), "v"(b));
    return d;
}

// ---------------- pre-kernel: per-oc counting sort + weight gather ----------------
// ws record per entry (12 floats, 48B): w0..w8, bias, chan(bits), pad
__global__ __launch_bounds__(64)
void rptn_presort(const float* __restrict__ w, const float* __restrict__ bias,
                  const int* __restrict__ idx, float* __restrict__ ws_w) {
    const int oc = blockIdx.x;
    const int t  = threadIdx.x;
    __shared__ int cnt[IN_CH], pos[IN_CH], eord[SET_LEN];

    if (t < IN_CH) cnt[t] = 0;
    __syncthreads();
    const int e = idx[oc * SET_LEN + t];
    const int c = e >> 8;
    atomicAdd(&cnt[c], 1);
    __syncthreads();
    if (t == 0) {
        int run = 0;
        for (int i = 0; i < IN_CH; ++i) { pos[i] = run; run += cnt[i]; }
    }
    __syncthreads();
    const int p = atomicAdd(&pos[c], 1);
    eord[p] = e;
    __syncthreads();

    const int    es  = eord[t];
    float*       dst = ws_w + ((size_t)oc * SET_LEN + t) * 12;
    const float* src = w + es * 9;
    #pragma unroll
    for (int i = 0; i < 9; ++i) dst[i] = src[i];
    dst[9]  = bias[es];
    dst[10] = __int_as_float(es >> 8);
    dst[11] = 0.0f;
}

// ---------------- main fused kernel (SGPR weights + packed VOP3P math) ----------------
__global__ __launch_bounds__(256, 2)
void rptn_fused_kernel(const float* __restrict__ x,
                       const float* __restrict__ ws_w,
                       float*       __restrict__ out) {
    const int oc   = blockIdx.x;   // fastest-varying -> x tile reused across oc in L2
    const int tile = blockIdx.y;
    const int b    = blockIdx.z;
    const int tid  = threadIdx.x;
    const int tx   = tid & 63;
    const int grp  = __builtin_amdgcn_readfirstlane(tid >> 6); // wave-uniform

    __shared__ float s_x[LDS_XN];

    // ---- stage x tile: aligned vec4 loads + vec4 LDS writes, fully pipelined ----
    const int r0 = tile * TILEROWS;
    const float* xb = x + (size_t)b * IN_CH * HH * WW;
    #pragma unroll
    for (int it = 0; it < 9; ++it) {
        const int v = tid + it * 256;
        if (it < 8 || v < NVEC) {                  // last round: tid<192
            const int c   = v / (LDSROWS * 14);
            const int rem = v - c * (LDSROWS * 14);
            const int r   = rem / 14;
            const int q   = rem - r * 14;
            const int gr  = r0 - 1 + r;
            f32x4 val = {0, 0, 0, 0};
            if ((unsigned)gr < (unsigned)HH)
                val = *(const f32x4*)(xb + (c * HH + gr) * WW + q * 4);
            *(f32x4*)&s_x[(c * LDSROWS + r) * LROW + q * 4] = val;
        }
    }
    __syncthreads();

    // ---- fused conv + bias + running max; 2 rows per lane, packed fp32 ----
    const bool  lanev = (tx < WW);
    const int   txr   = lanev ? tx : 0;            // clamp for safe LDS reads
    const int   txl   = (txr > 0)  ? txr - 1 : 0;  // in-row clamp; masked by lm
    const int   txp   = (txr < 55) ? txr + 1 : 55; // in-row clamp; masked by rm
    const float lm    = (txr == 0)  ? 0.0f : 1.0f; // left-edge tap mask
    const float rm    = (txr == 55) ? 0.0f : 1.0f; // right-edge tap mask

    f32x2 acc = { -__builtin_inff(), -__builtin_inff() };
    int ccur = -1;
    f32x2 v00={0,0},v01={0,0},v02={0,0};
    f32x2 v10={0,0},v11={0,0},v12={0,0};
    f32x2 v20={0,0},v21={0,0},v22={0,0};

    // uniform base -> s_load_dwordx4 per 16B record chunk, affine in k
    const ulonglong2* wt = (const ulonglong2*)ws_w + (size_t)oc * SET_LEN * 3;

    #pragma unroll 4
    for (int k = 0; k < SET_LEN; ++k) {
        const ulonglong2 A = wt[k * 3 + 0];   // {w0w1, w2w3}
        const ulonglong2 B = wt[k * 3 + 1];   // {w4w5, w6w7}
        const ulonglong2 C = wt[k * 3 + 2];   // {w8·bias, chan·pad}
        const int c = (int)(unsigned int)(C.y & 0xffffffffULL);
        if (c != ccur) {                      // wave-uniform branch (~16 of 64 iters)
            ccur = c;
            const float* sp = &s_x[(c * LDSROWS + grp * 2) * LROW];
            const float n00=sp[txl]*lm,        n01=sp[txr],        n02=sp[txp]*rm;
            const float n10=sp[LROW+txl]*lm,   n11=sp[LROW+txr],   n12=sp[LROW+txp]*rm;
            const float n20=sp[2*LROW+txl]*lm, n21=sp[2*LROW+txr], n22=sp[2*LROW+txp]*rm;
            const float n30=sp[3*LROW+txl]*lm, n31=sp[3*LROW+txr], n32=sp[3*LROW+txp]*rm;
            v00=(f32x2){n00,n10}; v01=(f32x2){n01,n11}; v02=(f32x2){n02,n12};
            v10=(f32x2){n10,n20}; v11=(f32x2){n11,n21}; v12=(f32x2){n12,n22};
            v20=(f32x2){n20,n30}; v21=(f32x2){n21,n31}; v22=(f32x2){n22,n32};
        }
        // 9 packed FMA/MUL with SGPR-half broadcast + 3 packed adds = 12 VALU / 2 px
        f32x2 t0 = pk_mul_slo(A.x, v00);          // w0
        t0       = pk_fma_shi(A.x, v01, t0);      // w1
        t0       = pk_fma_slo(A.y, v02, t0);      // w2
        f32x2 t1 = pk_mul_shi(A.y, v10);          // w3
        t1       = pk_fma_slo(B.x, v11, t1);      // w4
        t1       = pk_fma_shi(B.x, v12, t1);      // w5
        f32x2 t2 = pk_mul_slo(B.y, v20);          // w6
        t2       = pk_fma_shi(B.y, v21, t2);      // w7
        t2       = pk_fma_slo(C.x, v22, t2);      // w8
        f32x2 s  = pk_add_vv(t0, t1);
        s        = pk_add_vv(s, t2);
        s        = pk_add_shi(C.x, s);            // + bias
        acc.x = fmaxf(acc.x, s.x);
        acc.y = fmaxf(acc.y, s.y);
    }

    if (lanev) {
        const size_t o = (((size_t)b * OUT_CH + oc) * HH + (r0 + grp * 2)) * WW + tx;
        out[o]      = acc.x;   // row grp*2
        out[o + WW] = acc.y;   // row grp*2 + 1
    }
}

// ---------------- fallback (R9-style): in-block sort + LDS weight table ----------------
__global__ __launch_bounds__(256, 2)
void rptn_fused_fallback(const float* __restrict__ x,
                         const float* __restrict__ w,
                         const float* __restrict__ bias,
                         const int*   __restrict__ idx,
                         float*       __restrict__ out) {
    const int oc   = blockIdx.x;
    const int tile = blockIdx.y;
    const int b    = blockIdx.z;
    const int tid  = threadIdx.x;
    const int tx   = tid & 63;
    const int grp  = __builtin_amdgcn_readfirstlane(tid >> 6);

    __shared__ float s_x[LDS_XN];
    __shared__ f32x4 s_w[SET_LEN * 3];
    __shared__ int   s_cnt[IN_CH];
    __shared__ int   s_pos[IN_CH];
    __shared__ int   s_eord[SET_LEN];

    if (tid < IN_CH) s_cnt[tid] = 0;
    __syncthreads();
    int my_e = 0;
    if (tid < SET_LEN) {
        my_e = idx[oc * SET_LEN + tid];
        atomicAdd(&s_cnt[my_e >> 8], 1);
    }
    __syncthreads();
    if (tid == 0) {
        int run = 0;
        for (int c = 0; c < IN_CH; ++c) { s_pos[c] = run; run += s_cnt[c]; }
    }
    __syncthreads();
    if (tid < SET_LEN) {
        int p = atomicAdd(&s_pos[my_e >> 8], 1);
        s_eord[p] = my_e;
    }
    __syncthreads();

    float* s_wf = (float*)s_w;
    for (int i = tid; i < SET_LEN * 12; i += 256) {
        const int j    = i / 12;
        const int comp = i - j * 12;
        const int e    = s_eord[j];
        float v;
        if (comp < 9)        v = w[e * 9 + comp];
        else if (comp == 9)  v = bias[e];
        else if (comp == 10) v = __int_as_float(e >> 8);
        else                 v = 0.0f;
        s_wf[j * 12 + comp] = v;
    }

    const int r0 = tile * TILEROWS;
    const float* xb = x + (size_t)b * IN_CH * HH * WW;
    #pragma unroll
    for (int it = 0; it < 9; ++it) {
        const int v = tid + it * 256;
        if (it < 8 || v < NVEC) {
            const int c   = v / (LDSROWS * 14);
            const int rem = v - c * (LDSROWS * 14);
            const int r   = rem / 14;
            const int q   = rem - r * 14;
            const int gr  = r0 - 1 + r;
            f32x4 val = {0, 0, 0, 0};
            if ((unsigned)gr < (unsigned)HH)
                val = *(const f32x4*)(xb + (c * HH + gr) * WW + q * 4);
            *(f32x4*)&s_x[(c * LDSROWS + r) * LROW + q * 4] = val;
        }
    }
    __syncthreads();

    const bool  lanev = (tx < WW);
    const int   txr   = lanev ? tx : 0;
    const int   txl   = (txr > 0)  ? txr - 1 : 0;
    const int   txp   = (txr < 55) ? txr + 1 : 55;
    const float lm    = (txr == 0)  ? 0.0f : 1.0f;
    const float rm    = (txr == 55) ? 0.0f : 1.0f;

    f32x2 acc = { -__builtin_inff(), -__builtin_inff() };
    int ccur = -1;
    f32x2 v00={0,0},v01={0,0},v02={0,0};
    f32x2 v10={0,0},v11={0,0},v12={0,0};
    f32x2 v20={0,0},v21={0,0},v22={0,0};

    #pragma unroll 2
    for (int k = 0; k < SET_LEN; ++k) {
        const f32x4 q0 = s_w[k * 3 + 0];
        const f32x4 q1 = s_w[k * 3 + 1];
        const f32x4 q2 = s_w[k * 3 + 2];
        const int c = __float_as_int(q2.z);
        if (c != ccur) {
            ccur = c;
            const float* sp = &s_x[(c * LDSROWS + grp * 2) * LROW];
            const float n00=sp[txl]*lm,        n01=sp[txr],        n02=sp[txp]*rm;
            const float n10=sp[LROW+txl]*lm,   n11=sp[LROW+txr],   n12=sp[LROW+txp]*rm;
            const float n20=sp[2*LROW+txl]*lm, n21=sp[2*LROW+txr], n22=sp[2*LROW+txp]*rm;
            const float n30=sp[3*LROW+txl]*lm, n31=sp[3*LROW+txr], n32=sp[3*LROW+txp]*rm;
            v00=(f32x2){n00,n10}; v01=(f32x2){n01,n11}; v02=(f32x2){n02,n12};
            v10=(f32x2){n10,n20}; v11=(f32x2){n11,n21}; v12=(f32x2){n12,n22};
            v20=(f32x2){n20,n30}; v21=(f32x2){n21,n31}; v22=(f32x2){n22,n32};
        }
        f32x2 t0 = __builtin_elementwise_fma(splat2(q0.z), v02,
                   __builtin_elementwise_fma(splat2(q0.y), v01,
                   __builtin_elementwise_fma(splat2(q0.x), v00, splat2(q2.y))));
        f32x2 t1 = __builtin_elementwise_fma(splat2(q1.y), v12,
                   __builtin_elementwise_fma(splat2(q1.x), v11,
                                             splat2(q0.w) * v10));
        f32x2 t2 = __builtin_elementwise_fma(splat2(q2.x), v22,
                   __builtin_elementwise_fma(splat2(q1.w), v21,
                                             splat2(q1.z) * v20));
        const f32x2 s = t0 + (t1 + t2);
        acc.x = fmaxf(acc.x, s.x);
        acc.y = fmaxf(acc.y, s.y);
    }

    if (lanev) {
        const size_t o = (((size_t)b * OUT_CH + oc) * HH + (r0 + grp * 2)) * WW + tx;
        out[o]      = acc.x;
        out[o + WW] = acc.y;
    }
}

extern "C" void kernel_launch(void* const* d_in, const int* in_sizes, int n_in,
                              void* d_out, int out_size, void* d_ws, size_t ws_size,
                              hipStream_t stream) {
    const float* x    = (const float*)d_in[0];
    const float* w    = (const float*)d_in[1];
    const float* bias = (const float*)d_in[2];
    const int*   idx  = (const int*)d_in[3];
    float*       out  = (float*)d_out;

    dim3 grid(OUT_CH, NTILES, BB);   // oc fastest -> x tile L2 reuse
    dim3 block(256);

    if (ws_size >= (size_t)WS_NEEDED) {
        float* ws_w = (float*)d_ws;
        rptn_presort<<<dim3(OUT_CH), dim3(64), 0, stream>>>(w, bias, idx, ws_w);
        rptn_fused_kernel<<<grid, block, 0, stream>>>(x, ws_w, out);
    } else {
        rptn_fused_fallback<<<grid, block, 0, stream>>>(x, w, bias, idx, out);
    }
}